// Round 2
// baseline (520.403 us; speedup 1.0000x reference)
//
#include <hip/hip_runtime.h>

typedef __attribute__((ext_vector_type(8))) short bf16x8;
typedef __attribute__((ext_vector_type(4))) float f32x4;

__device__ __forceinline__ float b2f(ushort s) { return __uint_as_float(((uint)s) << 16); }
__device__ __forceinline__ ushort f2b(float f) {
  uint u = __float_as_uint(f);
  u += 0x7fff + ((u >> 16) & 1);   // RNE
  return (ushort)(u >> 16);
}

__device__ __forceinline__ void store_h(float* p, float v) { *p = v; }
__device__ __forceinline__ void store_h(ushort* p, float v) { *p = f2b(v); }

// ---------------- transpose+cast: in (R x C) f32 -> out (C x R) bf16 ----------------
__global__ void transpose_kernel(const float* __restrict__ in, ushort* __restrict__ out,
                                 int R, int C) {
  __shared__ ushort tile[32][33];
  int bc = blockIdx.x << 5;
  int br = blockIdx.y << 5;
  int tx = threadIdx.x & 31;
  int ty = threadIdx.x >> 5;  // 0..7
#pragma unroll
  for (int i = 0; i < 32; i += 8)
    tile[ty + i][tx] = f2b(in[(size_t)(br + ty + i) * C + bc + tx]);
  __syncthreads();
#pragma unroll
  for (int i = 0; i < 32; i += 8)
    out[(size_t)(bc + ty + i) * R + br + tx] = tile[tx][ty + i];
}

// ---------------- embedding gather+cast: x[r][:] = bf16(emb[tok[r]][:]), 512 elems ------
__global__ void embed_kernel(const int* __restrict__ tok, const float* __restrict__ emb,
                             ushort* __restrict__ x) {
  int tid = threadIdx.x;
  int r = (blockIdx.x << 2) + (tid >> 6);  // 4 rows per block
  int c = (tid & 63) << 3;                 // 8 elems per thread
  int t = tok[r];
  const float* src = emb + ((size_t)t << 9) + c;
  float4 a = *(const float4*)src;
  float4 b = *(const float4*)(src + 4);
  uint4 o;
  o.x = (uint)f2b(a.x) | ((uint)f2b(a.y) << 16);
  o.y = (uint)f2b(a.z) | ((uint)f2b(a.w) << 16);
  o.z = (uint)f2b(b.x) | ((uint)f2b(b.y) << 16);
  o.w = (uint)f2b(b.z) | ((uint)f2b(b.w) << 16);
  *(uint4*)(x + ((size_t)r << 9) + c) = o;
}

// ---------------- GEMM: C(MxN) bf16 = A(MxK) bf16 row-major * BT(NxK) bf16 row-major ---
// 128x128 tile, BK=64, 256 threads (2x2 waves of 64x64), 16x16x32 MFMA, f32 accum.
// LDS XOR-swizzle (byte ^= (row&7)<<4) applied identically on write and read.
__global__ __launch_bounds__(256) void gemm_bt_kernel(
    const ushort* __restrict__ A, const ushort* __restrict__ BT,
    ushort* __restrict__ C, int M, int N, int K) {
  __shared__ ushort As[128 * 64];
  __shared__ ushort Bs[128 * 64];
  const int tid = threadIdx.x;
  const int lane = tid & 63;
  const int wave = tid >> 6;
  const int wm = (wave >> 1) << 6;
  const int wn = (wave & 1) << 6;
  const int m0 = blockIdx.x << 7;
  const int n0 = blockIdx.y << 7;

  f32x4 acc[4][4];
#pragma unroll
  for (int i = 0; i < 4; ++i)
#pragma unroll
    for (int j = 0; j < 4; ++j) acc[i][j] = (f32x4){0.f, 0.f, 0.f, 0.f};

  for (int k0 = 0; k0 < K; k0 += 64) {
#pragma unroll
    for (int i = 0; i < 4; ++i) {
      int linear = tid + (i << 8);        // 0..1023 chunks of 16B
      int row = linear >> 3;              // 0..127
      int col = (linear & 7) << 3;        // 0,8,..,56
      int byte = ((row << 6) + col) * 2;
      byte ^= (row & 7) << 4;
      *(uint4*)((char*)As + byte) = *(const uint4*)(A + (size_t)(m0 + row) * K + k0 + col);
      *(uint4*)((char*)Bs + byte) = *(const uint4*)(BT + (size_t)(n0 + row) * K + k0 + col);
    }
    __syncthreads();
#pragma unroll
    for (int kk = 0; kk < 2; ++kk) {
      const int kof = (kk << 5) + ((lane >> 4) << 3);
      bf16x8 af[4], bg[4];
#pragma unroll
      for (int mi = 0; mi < 4; ++mi) {
        int row = wm + (mi << 4) + (lane & 15);
        int byte = ((row << 6) + kof) * 2;
        byte ^= (row & 7) << 4;
        af[mi] = *(const bf16x8*)((const char*)As + byte);
      }
#pragma unroll
      for (int ni = 0; ni < 4; ++ni) {
        int row = wn + (ni << 4) + (lane & 15);
        int byte = ((row << 6) + kof) * 2;
        byte ^= (row & 7) << 4;
        bg[ni] = *(const bf16x8*)((const char*)Bs + byte);
      }
#pragma unroll
      for (int mi = 0; mi < 4; ++mi)
#pragma unroll
        for (int ni = 0; ni < 4; ++ni)
          acc[mi][ni] =
              __builtin_amdgcn_mfma_f32_16x16x32_bf16(af[mi], bg[ni], acc[mi][ni], 0, 0, 0);
    }
    __syncthreads();
  }
  // epilogue: D row=(lane>>4)*4+j, col=lane&15 (m89-verified)
#pragma unroll
  for (int mi = 0; mi < 4; ++mi) {
#pragma unroll
    for (int j = 0; j < 4; ++j) {
      int row = m0 + wm + (mi << 4) + ((lane >> 4) << 2) + j;
      size_t base = (size_t)row * N + n0 + wn;
#pragma unroll
      for (int ni = 0; ni < 4; ++ni)
        C[base + (ni << 4) + (lane & 15)] = f2b(acc[mi][ni][j]);
    }
  }
}

// ---------------- SRU bidirectional scan ----------------
// One thread per (b, dir, h) channel. dir0: t ascending; dir1: t descending (the two
// _flip_bwd's reduce to iteration direction). KC=4: highway = u[...,3]; KC=3: highway = xres.
template <int KC, typename OT>
__global__ void sru_scan_kernel(const ushort* __restrict__ u, const float* __restrict__ bias,
                                const ushort* __restrict__ xres, OT* __restrict__ hout,
                                float* __restrict__ cout) {
  const int L = 256, B = 64, H = 512;
  int idx = blockIdx.x * 256 + threadIdx.x;  // 65536 = B*2*H
  int h = idx & (H - 1);
  int dir = (idx >> 9) & 1;
  int b = idx >> 10;
  float bfg = bias[dir * H + h];        // bias[0][dir][h]
  float brg = bias[2 * H + dir * H + h];  // bias[1][dir][h]
  const size_t ustep = (size_t)B * 2 * H * KC;
  const ushort* ubase = u + ((size_t)b * 2 + dir) * H * KC + (size_t)h * KC;
  const size_t hstep = (size_t)B * 2 * H;
  const size_t hoff = (size_t)b * 2 * H + (size_t)dir * H + h;
  float c = 0.f;
#pragma unroll 8
  for (int s = 0; s < L; ++s) {
    int t = dir ? (L - 1 - s) : s;
    const ushort* up = ubase + (size_t)t * ustep;
    float xt, fg, rg, xr;
    if (KC == 4) {
      uint2 v = *(const uint2*)up;
      xt = b2f((ushort)(v.x & 0xffff));
      fg = b2f((ushort)(v.x >> 16));
      rg = b2f((ushort)(v.y & 0xffff));
      xr = b2f((ushort)(v.y >> 16));
    } else {
      xt = b2f(up[0]);
      fg = b2f(up[1]);
      rg = b2f(up[2]);
      xr = b2f(xres[hoff + (size_t)t * hstep]);
    }
    float f = 1.f / (1.f + expf(-(fg + bfg)));
    float r = 1.f / (1.f + expf(-(rg + brg)));
    c = f * c + (1.f - f) * xt;
    float hv = r * tanhf(c) + (1.f - r) * xr;
    store_h(hout + hoff + (size_t)t * hstep, hv);
  }
  cout[(size_t)b * 2 * H + (size_t)dir * H + h] = c;
}

// ---------------- dense_hidden: out[row][j] = c12[row][:] . Wd[j][:] + bd[j] ----------------
__global__ void dense_kernel(const float* __restrict__ c12, const float* __restrict__ Wd,
                             const float* __restrict__ bd, float* __restrict__ out) {
  int idx = blockIdx.x * 256 + threadIdx.x;  // 65536 = 2*64*512
  int j = idx & 511;
  int row = idx >> 9;  // layer*64 + b
  const float* c = c12 + (size_t)row * 1024;
  const float* w = Wd + (size_t)j * 1024;
  float acc = bd[j];
  for (int k = 0; k < 1024; k += 4) {
    float4 wv = *(const float4*)(w + k);
    float4 cv = *(const float4*)(c + k);
    acc += cv.x * wv.x + cv.y * wv.y + cv.z * wv.z + cv.w * wv.w;
  }
  out[idx] = acc;
}

extern "C" void kernel_launch(void* const* d_in, const int* in_sizes, int n_in,
                              void* d_out, int out_size, void* d_ws, size_t ws_size,
                              hipStream_t stream) {
  const int* tok = (const int*)d_in[0];
  const float* emb = (const float*)d_in[1];
  const float* W0 = (const float*)d_in[2];
  const float* b0 = (const float*)d_in[3];
  const float* W1 = (const float*)d_in[4];
  const float* b1 = (const float*)d_in[5];
  const float* Wd = (const float*)d_in[6];
  const float* bd = (const float*)d_in[7];
  float* out = (float*)d_out;

  char* ws = (char*)d_ws;
  ushort* x = (ushort*)ws;                        //  16,777,216 B  (16384 x 512 bf16)
  ushort* W0T = (ushort*)(ws + 16777216);         //   4,194,304 B  (4096 x 512 bf16)
  ushort* W1T = (ushort*)(ws + 20971520);         //   6,291,456 B  (3072 x 1024 bf16)
  ushort* u = (ushort*)(ws + 27262976);           // 134,217,728 B  (u0 / u1 aliased, bf16)
  ushort* h1 = (ushort*)(ws + 161480704);         //  33,554,432 B  (16384 x 1024 bf16)
  float* c12 = (float*)(ws + 195035136);          //     524,288 B  (2 x 64 x 1024 f32)
  // total: 195,559,424 B

  // W transposes -> N x K bf16 layout for gemm_bt
  transpose_kernel<<<dim3(128, 16), 256, 0, stream>>>(W0, W0T, 512, 4096);
  transpose_kernel<<<dim3(96, 32), 256, 0, stream>>>(W1, W1T, 1024, 3072);
  // x = bf16(emb[tokens])
  embed_kernel<<<4096, 256, 0, stream>>>(tok, emb, x);
  // u0 = x @ W0   (16384 x 4096)
  gemm_bt_kernel<<<dim3(128, 32), 256, 0, stream>>>(x, W0T, u, 16384, 4096, 512);
  // layer0 scan (k=4) -> h1 (bf16), c1
  sru_scan_kernel<4, ushort><<<256, 256, 0, stream>>>(u, b0, (const ushort*)nullptr, h1, c12);
  // u1 = h1 @ W1  (16384 x 3072)
  gemm_bt_kernel<<<dim3(128, 24), 256, 0, stream>>>(h1, W1T, u, 16384, 3072, 1024);
  // layer1 scan (k=3) -> h2 (f32, direct to d_out), c2
  sru_scan_kernel<3, float><<<256, 256, 0, stream>>>(u, b1, h1, out, c12 + 65536);
  // hidden = [c1;c2] @ Wd.T + bd -> d_out tail (f32)
  dense_kernel<<<256, 256, 0, stream>>>(c12, Wd, bd, out + 16777216);
}

// Round 3
// 484.160 us; speedup vs baseline: 1.0749x; 1.0749x over previous
//
#include <hip/hip_runtime.h>

typedef __attribute__((ext_vector_type(8))) short bf16x8;
typedef __attribute__((ext_vector_type(4))) float f32x4;

__device__ __forceinline__ float b2f(ushort s) { return __uint_as_float(((uint)s) << 16); }
__device__ __forceinline__ ushort f2b(float f) {
  uint u = __float_as_uint(f);
  u += 0x7fff + ((u >> 16) & 1);   // RNE
  return (ushort)(u >> 16);
}

__device__ __forceinline__ void store_h(float* p, float v) { *p = v; }
__device__ __forceinline__ void store_h(ushort* p, float v) { *p = f2b(v); }

// ---------------- transpose+cast: in (R x C) f32 -> out (C x R) bf16 ----------------
__global__ void transpose_kernel(const float* __restrict__ in, ushort* __restrict__ out,
                                 int R, int C) {
  __shared__ ushort tile[32][33];
  int bc = blockIdx.x << 5;
  int br = blockIdx.y << 5;
  int tx = threadIdx.x & 31;
  int ty = threadIdx.x >> 5;  // 0..7
#pragma unroll
  for (int i = 0; i < 32; i += 8)
    tile[ty + i][tx] = f2b(in[(size_t)(br + ty + i) * C + bc + tx]);
  __syncthreads();
#pragma unroll
  for (int i = 0; i < 32; i += 8)
    out[(size_t)(bc + ty + i) * R + br + tx] = tile[tx][ty + i];
}

// ---------------- embedding gather+cast: x[r][:] = bf16(emb[tok[r]][:]), 512 elems ------
__global__ void embed_kernel(const int* __restrict__ tok, const float* __restrict__ emb,
                             ushort* __restrict__ x) {
  int tid = threadIdx.x;
  int r = (blockIdx.x << 2) + (tid >> 6);  // 4 rows per block
  int c = (tid & 63) << 3;                 // 8 elems per thread
  int t = tok[r];
  const float* src = emb + ((size_t)t << 9) + c;
  float4 a = *(const float4*)src;
  float4 b = *(const float4*)(src + 4);
  uint4 o;
  o.x = (uint)f2b(a.x) | ((uint)f2b(a.y) << 16);
  o.y = (uint)f2b(a.z) | ((uint)f2b(a.w) << 16);
  o.z = (uint)f2b(b.x) | ((uint)f2b(b.y) << 16);
  o.w = (uint)f2b(b.z) | ((uint)f2b(b.w) << 16);
  *(uint4*)(x + ((size_t)r << 9) + c) = o;
}

// ---------------- GEMM: C(MxN) bf16 = A(MxK) bf16 row-major * BT(NxK) bf16 row-major ---
// 128x128 tile, BK=64, 256 threads (2x2 waves of 64x64), 16x16x32 MFMA, f32 accum.
// Staging: global_load_lds width=16, LINEAR LDS dest + inverse-swizzled per-lane global
// source (rule m173/m201); reads use byte ^= (row&7)<<4 -> 0 bank conflicts.
__global__ __launch_bounds__(256) void gemm_bt_kernel(
    const ushort* __restrict__ A, const ushort* __restrict__ BT,
    ushort* __restrict__ C, int M, int N, int K) {
  __shared__ ushort As[128 * 64];
  __shared__ ushort Bs[128 * 64];
  const int tid = threadIdx.x;
  const int lane = tid & 63;
  const int wave = tid >> 6;
  const int wm = (wave >> 1) << 6;
  const int wn = (wave & 1) << 6;
  const int m0 = blockIdx.x << 7;
  const int n0 = blockIdx.y << 7;

  f32x4 acc[4][4];
#pragma unroll
  for (int i = 0; i < 4; ++i)
#pragma unroll
    for (int j = 0; j < 4; ++j) acc[i][j] = (f32x4){0.f, 0.f, 0.f, 0.f};

  // wave w stages physical LDS bytes [w*4096, (w+1)*4096) of each tile, in 4 insts of 1KB.
  // physical byte p holds logical byte p ^ ((row&7)<<4), row = p>>7 (swizzle preserves row).
  const int wbase = wave << 12;
  for (int k0 = 0; k0 < K; k0 += 64) {
#pragma unroll
    for (int i = 0; i < 4; ++i) {
      int p = wbase + (i << 10) + (lane << 4);
      int row = p >> 7;                               // 0..127
      int col = ((p & 127) ^ ((row & 7) << 4)) >> 1;  // bf16 col 0..63
      const ushort* ga = A + (size_t)(m0 + row) * K + k0 + col;
      const ushort* gb = BT + (size_t)(n0 + row) * K + k0 + col;
      __builtin_amdgcn_global_load_lds(
          (const __attribute__((address_space(1))) void*)ga,
          (__attribute__((address_space(3))) void*)((char*)As + wbase + (i << 10)), 16, 0, 0);
      __builtin_amdgcn_global_load_lds(
          (const __attribute__((address_space(1))) void*)gb,
          (__attribute__((address_space(3))) void*)((char*)Bs + wbase + (i << 10)), 16, 0, 0);
    }
    __syncthreads();
#pragma unroll
    for (int kk = 0; kk < 2; ++kk) {
      const int kof = (kk << 5) + ((lane >> 4) << 3);
      bf16x8 af[4], bg[4];
#pragma unroll
      for (int mi = 0; mi < 4; ++mi) {
        int row = wm + (mi << 4) + (lane & 15);
        int byte = ((row << 6) + kof) * 2;
        byte ^= (row & 7) << 4;
        af[mi] = *(const bf16x8*)((const char*)As + byte);
      }
#pragma unroll
      for (int ni = 0; ni < 4; ++ni) {
        int row = wn + (ni << 4) + (lane & 15);
        int byte = ((row << 6) + kof) * 2;
        byte ^= (row & 7) << 4;
        bg[ni] = *(const bf16x8*)((const char*)Bs + byte);
      }
#pragma unroll
      for (int mi = 0; mi < 4; ++mi)
#pragma unroll
        for (int ni = 0; ni < 4; ++ni)
          acc[mi][ni] =
              __builtin_amdgcn_mfma_f32_16x16x32_bf16(af[mi], bg[ni], acc[mi][ni], 0, 0, 0);
    }
    __syncthreads();
  }
  // epilogue: D row=(lane>>4)*4+j, col=lane&15 (m89-verified)
#pragma unroll
  for (int mi = 0; mi < 4; ++mi) {
#pragma unroll
    for (int j = 0; j < 4; ++j) {
      int row = m0 + wm + (mi << 4) + ((lane >> 4) << 2) + j;
      size_t base = (size_t)row * N + n0 + wn;
#pragma unroll
      for (int ni = 0; ni < 4; ++ni)
        C[base + (ni << 4) + (lane & 15)] = f2b(acc[mi][ni][j]);
    }
  }
}

// ---------------- SRU bidirectional scan ----------------
// One thread per (b, dir, h) channel. dir0: t ascending; dir1: t descending (the two
// _flip_bwd's reduce to iteration direction). KC=4: highway = u[...,3]; KC=3: highway = xres.
template <int KC, typename OT>
__global__ void sru_scan_kernel(const ushort* __restrict__ u, const float* __restrict__ bias,
                                const ushort* __restrict__ xres, OT* __restrict__ hout,
                                float* __restrict__ cout) {
  const int L = 256, B = 64, H = 512;
  int idx = blockIdx.x * 256 + threadIdx.x;  // 65536 = B*2*H
  int h = idx & (H - 1);
  int dir = (idx >> 9) & 1;
  int b = idx >> 10;
  float bfg = bias[dir * H + h];          // bias[0][dir][h]
  float brg = bias[2 * H + dir * H + h];  // bias[1][dir][h]
  const size_t ustep = (size_t)B * 2 * H * KC;
  const ushort* ubase = u + ((size_t)b * 2 + dir) * H * KC + (size_t)h * KC;
  const size_t hstep = (size_t)B * 2 * H;
  const size_t hoff = (size_t)b * 2 * H + (size_t)dir * H + h;
  float c = 0.f;
#pragma unroll 8
  for (int s = 0; s < L; ++s) {
    int t = dir ? (L - 1 - s) : s;
    const ushort* up = ubase + (size_t)t * ustep;
    float xt, fg, rg, xr;
    if (KC == 4) {
      uint2 v = *(const uint2*)up;
      xt = b2f((ushort)(v.x & 0xffff));
      fg = b2f((ushort)(v.x >> 16));
      rg = b2f((ushort)(v.y & 0xffff));
      xr = b2f((ushort)(v.y >> 16));
    } else {
      xt = b2f(up[0]);
      fg = b2f(up[1]);
      rg = b2f(up[2]);
      xr = b2f(xres[hoff + (size_t)t * hstep]);
    }
    float f = 1.f / (1.f + expf(-(fg + bfg)));
    float r = 1.f / (1.f + expf(-(rg + brg)));
    c = f * c + (1.f - f) * xt;
    float hv = r * tanhf(c) + (1.f - r) * xr;
    store_h(hout + hoff + (size_t)t * hstep, hv);
  }
  cout[(size_t)b * 2 * H + (size_t)dir * H + h] = c;
}

// ---------------- dense_hidden: out[row][j] = c12[row][:] . Wd[j][:] + bd[j] ----------------
__global__ void dense_kernel(const float* __restrict__ c12, const float* __restrict__ Wd,
                             const float* __restrict__ bd, float* __restrict__ out) {
  int idx = blockIdx.x * 256 + threadIdx.x;  // 65536 = 2*64*512
  int j = idx & 511;
  int row = idx >> 9;  // layer*64 + b
  const float* c = c12 + (size_t)row * 1024;
  const float* w = Wd + (size_t)j * 1024;
  float acc = bd[j];
  for (int k = 0; k < 1024; k += 4) {
    float4 wv = *(const float4*)(w + k);
    float4 cv = *(const float4*)(c + k);
    acc += cv.x * wv.x + cv.y * wv.y + cv.z * wv.z + cv.w * wv.w;
  }
  out[idx] = acc;
}

extern "C" void kernel_launch(void* const* d_in, const int* in_sizes, int n_in,
                              void* d_out, int out_size, void* d_ws, size_t ws_size,
                              hipStream_t stream) {
  const int* tok = (const int*)d_in[0];
  const float* emb = (const float*)d_in[1];
  const float* W0 = (const float*)d_in[2];
  const float* b0 = (const float*)d_in[3];
  const float* W1 = (const float*)d_in[4];
  const float* b1 = (const float*)d_in[5];
  const float* Wd = (const float*)d_in[6];
  const float* bd = (const float*)d_in[7];
  float* out = (float*)d_out;

  char* ws = (char*)d_ws;
  ushort* x = (ushort*)ws;                        //  16,777,216 B  (16384 x 512 bf16)
  ushort* W0T = (ushort*)(ws + 16777216);         //   4,194,304 B  (4096 x 512 bf16)
  ushort* W1T = (ushort*)(ws + 20971520);         //   6,291,456 B  (3072 x 1024 bf16)
  ushort* u = (ushort*)(ws + 27262976);           // 134,217,728 B  (u0 / u1 aliased, bf16)
  ushort* h1 = (ushort*)(ws + 161480704);         //  33,554,432 B  (16384 x 1024 bf16)
  float* c12 = (float*)(ws + 195035136);          //     524,288 B  (2 x 64 x 1024 f32)
  // total: 195,559,424 B

  // W transposes -> N x K bf16 layout for gemm_bt
  transpose_kernel<<<dim3(128, 16), 256, 0, stream>>>(W0, W0T, 512, 4096);
  transpose_kernel<<<dim3(96, 32), 256, 0, stream>>>(W1, W1T, 1024, 3072);
  // x = bf16(emb[tokens])
  embed_kernel<<<4096, 256, 0, stream>>>(tok, emb, x);
  // u0 = x @ W0   (16384 x 4096)
  gemm_bt_kernel<<<dim3(128, 32), 256, 0, stream>>>(x, W0T, u, 16384, 4096, 512);
  // layer0 scan (k=4) -> h1 (bf16), c1
  sru_scan_kernel<4, ushort><<<256, 256, 0, stream>>>(u, b0, (const ushort*)nullptr, h1, c12);
  // u1 = h1 @ W1  (16384 x 3072)
  gemm_bt_kernel<<<dim3(128, 24), 256, 0, stream>>>(h1, W1T, u, 16384, 3072, 1024);
  // layer1 scan (k=3) -> h2 (f32, direct to d_out), c2
  sru_scan_kernel<3, float><<<256, 256, 0, stream>>>(u, b1, h1, out, c12 + 65536);
  // hidden = [c1;c2] @ Wd.T + bd -> d_out tail (f32)
  dense_kernel<<<256, 256, 0, stream>>>(c12, Wd, bd, out + 16777216);
}

// Round 4
// 394.623 us; speedup vs baseline: 1.3187x; 1.2269x over previous
//
#include <hip/hip_runtime.h>

typedef __attribute__((ext_vector_type(8))) short bf16x8;
typedef __attribute__((ext_vector_type(4))) float f32x4;

__device__ __forceinline__ float b2f(ushort s) { return __uint_as_float(((uint)s) << 16); }
__device__ __forceinline__ ushort f2b(float f) {
  uint u = __float_as_uint(f);
  u += 0x7fff + ((u >> 16) & 1);   // RNE
  return (ushort)(u >> 16);
}

__device__ __forceinline__ void store_h(float* p, float v) { *p = v; }
__device__ __forceinline__ void store_h(ushort* p, float v) { *p = f2b(v); }

// fast sigmoid/tanh: v_exp_f32-based, ~1ulp — error ~1e-7, negligible vs bf16 inputs
__device__ __forceinline__ float sigm_fast(float x) { return 1.f / (1.f + __expf(-x)); }
__device__ __forceinline__ float tanh_fast(float c) {
  float e = __expf(-2.f * fabsf(c));
  float t = (1.f - e) / (1.f + e);
  return copysignf(t, c);
}

// ---------------- transpose+cast: in (R x C) f32 -> out (C x R) bf16 ----------------
__global__ void transpose_kernel(const float* __restrict__ in, ushort* __restrict__ out,
                                 int R, int C) {
  __shared__ ushort tile[32][33];
  int bc = blockIdx.x << 5;
  int br = blockIdx.y << 5;
  int tx = threadIdx.x & 31;
  int ty = threadIdx.x >> 5;  // 0..7
#pragma unroll
  for (int i = 0; i < 32; i += 8)
    tile[ty + i][tx] = f2b(in[(size_t)(br + ty + i) * C + bc + tx]);
  __syncthreads();
#pragma unroll
  for (int i = 0; i < 32; i += 8)
    out[(size_t)(bc + ty + i) * R + br + tx] = tile[tx][ty + i];
}

// ---------------- embedding gather+cast: x[r][:] = bf16(emb[tok[r]][:]), 512 elems ------
__global__ void embed_kernel(const int* __restrict__ tok, const float* __restrict__ emb,
                             ushort* __restrict__ x) {
  int tid = threadIdx.x;
  int r = (blockIdx.x << 2) + (tid >> 6);  // 4 rows per block
  int c = (tid & 63) << 3;                 // 8 elems per thread
  int t = tok[r];
  const float* src = emb + ((size_t)t << 9) + c;
  float4 a = *(const float4*)src;
  float4 b = *(const float4*)(src + 4);
  uint4 o;
  o.x = (uint)f2b(a.x) | ((uint)f2b(a.y) << 16);
  o.y = (uint)f2b(a.z) | ((uint)f2b(a.w) << 16);
  o.z = (uint)f2b(b.x) | ((uint)f2b(b.y) << 16);
  o.w = (uint)f2b(b.z) | ((uint)f2b(b.w) << 16);
  *(uint4*)(x + ((size_t)r << 9) + c) = o;
}

// ---------------- GEMM: C(MxN) bf16 = A(MxK) bf16 row-major * BT(NxK) bf16 row-major ---
// 128x128 tile, BK=64, 256 threads (2x2 waves of 64x64), 16x16x32 MFMA, f32 accum.
// Staging: global_load_lds width=16, LINEAR LDS dest + inverse-swizzled per-lane global
// source (rule m173/m201); reads use byte ^= (row&7)<<4 -> 0 bank conflicts.
__global__ __launch_bounds__(256) void gemm_bt_kernel(
    const ushort* __restrict__ A, const ushort* __restrict__ BT,
    ushort* __restrict__ C, int M, int N, int K) {
  __shared__ ushort As[128 * 64];
  __shared__ ushort Bs[128 * 64];
  const int tid = threadIdx.x;
  const int lane = tid & 63;
  const int wave = tid >> 6;
  const int wm = (wave >> 1) << 6;
  const int wn = (wave & 1) << 6;
  const int m0 = blockIdx.x << 7;
  const int n0 = blockIdx.y << 7;

  f32x4 acc[4][4];
#pragma unroll
  for (int i = 0; i < 4; ++i)
#pragma unroll
    for (int j = 0; j < 4; ++j) acc[i][j] = (f32x4){0.f, 0.f, 0.f, 0.f};

  // wave w stages physical LDS bytes [w*4096, (w+1)*4096) of each tile, in 4 insts of 1KB.
  // physical byte p holds logical byte p ^ ((row&7)<<4), row = p>>7 (swizzle preserves row).
  const int wbase = wave << 12;
  for (int k0 = 0; k0 < K; k0 += 64) {
#pragma unroll
    for (int i = 0; i < 4; ++i) {
      int p = wbase + (i << 10) + (lane << 4);
      int row = p >> 7;                               // 0..127
      int col = ((p & 127) ^ ((row & 7) << 4)) >> 1;  // bf16 col 0..63
      const ushort* ga = A + (size_t)(m0 + row) * K + k0 + col;
      const ushort* gb = BT + (size_t)(n0 + row) * K + k0 + col;
      __builtin_amdgcn_global_load_lds(
          (const __attribute__((address_space(1))) void*)ga,
          (__attribute__((address_space(3))) void*)((char*)As + wbase + (i << 10)), 16, 0, 0);
      __builtin_amdgcn_global_load_lds(
          (const __attribute__((address_space(1))) void*)gb,
          (__attribute__((address_space(3))) void*)((char*)Bs + wbase + (i << 10)), 16, 0, 0);
    }
    __syncthreads();
#pragma unroll
    for (int kk = 0; kk < 2; ++kk) {
      const int kof = (kk << 5) + ((lane >> 4) << 3);
      bf16x8 af[4], bg[4];
#pragma unroll
      for (int mi = 0; mi < 4; ++mi) {
        int row = wm + (mi << 4) + (lane & 15);
        int byte = ((row << 6) + kof) * 2;
        byte ^= (row & 7) << 4;
        af[mi] = *(const bf16x8*)((const char*)As + byte);
      }
#pragma unroll
      for (int ni = 0; ni < 4; ++ni) {
        int row = wn + (ni << 4) + (lane & 15);
        int byte = ((row << 6) + kof) * 2;
        byte ^= (row & 7) << 4;
        bg[ni] = *(const bf16x8*)((const char*)Bs + byte);
      }
#pragma unroll
      for (int mi = 0; mi < 4; ++mi)
#pragma unroll
        for (int ni = 0; ni < 4; ++ni)
          acc[mi][ni] =
              __builtin_amdgcn_mfma_f32_16x16x32_bf16(af[mi], bg[ni], acc[mi][ni], 0, 0, 0);
    }
    __syncthreads();
  }
  // epilogue: D row=(lane>>4)*4+j, col=lane&15 (m89-verified)
#pragma unroll
  for (int mi = 0; mi < 4; ++mi) {
#pragma unroll
    for (int j = 0; j < 4; ++j) {
      int row = m0 + wm + (mi << 4) + ((lane >> 4) << 2) + j;
      size_t base = (size_t)row * N + n0 + wn;
#pragma unroll
      for (int ni = 0; ni < 4; ++ni)
        C[base + (ni << 4) + (lane & 15)] = f2b(acc[mi][ni][j]);
    }
  }
}

// ---------------- SRU bidirectional scan ----------------
// One thread per (b, dir, h) channel. dir0: t ascending; dir1: t descending (the two
// _flip_bwd's reduce to iteration direction). KC=4: highway = u[...,3]; KC=3: highway = xres.
template <int KC, typename OT>
__global__ void sru_scan_kernel(const ushort* __restrict__ u, const float* __restrict__ bias,
                                const ushort* __restrict__ xres, OT* __restrict__ hout,
                                float* __restrict__ cout) {
  const int L = 256, B = 64, H = 512;
  int idx = blockIdx.x * 256 + threadIdx.x;  // 65536 = B*2*H
  int h = idx & (H - 1);
  int dir = (idx >> 9) & 1;
  int b = idx >> 10;
  float bfg = bias[dir * H + h];          // bias[0][dir][h]
  float brg = bias[2 * H + dir * H + h];  // bias[1][dir][h]
  const size_t ustep = (size_t)B * 2 * H * KC;
  const ushort* ubase = u + ((size_t)b * 2 + dir) * H * KC + (size_t)h * KC;
  const size_t hstep = (size_t)B * 2 * H;
  const size_t hoff = (size_t)b * 2 * H + (size_t)dir * H + h;
  float c = 0.f;
#pragma unroll 16
  for (int s = 0; s < L; ++s) {
    int t = dir ? (L - 1 - s) : s;
    const ushort* up = ubase + (size_t)t * ustep;
    float xt, fg, rg, xr;
    if (KC == 4) {
      uint2 v = *(const uint2*)up;
      xt = b2f((ushort)(v.x & 0xffff));
      fg = b2f((ushort)(v.x >> 16));
      rg = b2f((ushort)(v.y & 0xffff));
      xr = b2f((ushort)(v.y >> 16));
    } else {
      xt = b2f(up[0]);
      fg = b2f(up[1]);
      rg = b2f(up[2]);
      xr = b2f(xres[hoff + (size_t)t * hstep]);
    }
    float f = sigm_fast(fg + bfg);
    float r = sigm_fast(rg + brg);
    c = f * c + (1.f - f) * xt;
    float hv = r * tanh_fast(c) + (1.f - r) * xr;
    store_h(hout + hoff + (size_t)t * hstep, hv);
  }
  cout[(size_t)b * 2 * H + (size_t)dir * H + h] = c;
}

// ---------------- dense_hidden: out[row][j] = c12[row][:] . WdT[:][j] + bd[j] ------------
// block = one row (128 blocks x 512 threads); lane j reads WdT[k][j] coalesced, c[k] uniform.
__global__ __launch_bounds__(512) void dense_kernel(
    const float* __restrict__ c12, const ushort* __restrict__ WdT,
    const float* __restrict__ bd, float* __restrict__ out) {
  int row = blockIdx.x;   // 0..127  (layer*64 + b)
  int j = threadIdx.x;    // 0..511
  const float* c = c12 + (size_t)row * 1024;
  float acc = bd[j];
#pragma unroll 8
  for (int k = 0; k < 1024; ++k) acc += c[k] * b2f(WdT[(size_t)k * 512 + j]);
  out[(size_t)row * 512 + j] = acc;
}

extern "C" void kernel_launch(void* const* d_in, const int* in_sizes, int n_in,
                              void* d_out, int out_size, void* d_ws, size_t ws_size,
                              hipStream_t stream) {
  const int* tok = (const int*)d_in[0];
  const float* emb = (const float*)d_in[1];
  const float* W0 = (const float*)d_in[2];
  const float* b0 = (const float*)d_in[3];
  const float* W1 = (const float*)d_in[4];
  const float* b1 = (const float*)d_in[5];
  const float* Wd = (const float*)d_in[6];
  const float* bd = (const float*)d_in[7];
  float* out = (float*)d_out;

  char* ws = (char*)d_ws;
  ushort* x = (ushort*)ws;                        //  16,777,216 B  (16384 x 512 bf16)
  ushort* W0T = (ushort*)(ws + 16777216);         //   4,194,304 B  (4096 x 512 bf16)
  ushort* W1T = (ushort*)(ws + 20971520);         //   6,291,456 B  (3072 x 1024 bf16)
  ushort* u = (ushort*)(ws + 27262976);           // 134,217,728 B  (u0 / u1 aliased, bf16)
  ushort* h1 = (ushort*)(ws + 161480704);         //  33,554,432 B  (16384 x 1024 bf16)
  float* c12 = (float*)(ws + 195035136);          //     524,288 B  (2 x 64 x 1024 f32)
  // WdT (1024x512 bf16 = 1 MB) lives in the dead tail of the u region: u1 occupies only
  // 100,663,296 B of u's 134,217,728 B; transpose runs after scan1 (u0 fully consumed).
  ushort* WdT = (ushort*)(ws + 27262976 + 100663296);
  // total: 195,559,424 B (unchanged)

  // W transposes -> N x K bf16 layout for gemm_bt
  transpose_kernel<<<dim3(128, 16), 256, 0, stream>>>(W0, W0T, 512, 4096);
  transpose_kernel<<<dim3(96, 32), 256, 0, stream>>>(W1, W1T, 1024, 3072);
  // x = bf16(emb[tokens])
  embed_kernel<<<4096, 256, 0, stream>>>(tok, emb, x);
  // u0 = x @ W0   (16384 x 4096)
  gemm_bt_kernel<<<dim3(128, 32), 256, 0, stream>>>(x, W0T, u, 16384, 4096, 512);
  // layer0 scan (k=4) -> h1 (bf16), c1
  sru_scan_kernel<4, ushort><<<256, 256, 0, stream>>>(u, b0, (const ushort*)nullptr, h1, c12);
  // u1 = h1 @ W1  (16384 x 3072)
  gemm_bt_kernel<<<dim3(128, 24), 256, 0, stream>>>(h1, W1T, u, 16384, 3072, 1024);
  // layer1 scan (k=3) -> h2 (f32, direct to d_out), c2
  sru_scan_kernel<3, float><<<256, 256, 0, stream>>>(u, b1, h1, out, c12 + 65536);
  // WdT = transpose(Wd) bf16  (after scan1: u-tail is dead)
  transpose_kernel<<<dim3(32, 16), 256, 0, stream>>>(Wd, WdT, 512, 1024);
  // hidden = [c1;c2] @ Wd.T + bd -> d_out tail (f32)
  dense_kernel<<<128, 512, 0, stream>>>(c12, WdT, bd, out + 16777216);
}